// Round 2
// baseline (222.912 us; speedup 1.0000x reference)
//
#include <hip/hip_runtime.h>
#include <hip/hip_bf16.h>

#define DMODEL 1024
#define NHEADS 16
#define HDIM   64
#define BATCH  2
#define SEQ    2048
#define XELEMS ((size_t)BATCH * SEQ * DMODEL)   // 4,194,304
#define WELEMS ((size_t)DMODEL * DMODEL)        // 1,048,576

typedef __attribute__((ext_vector_type(8))) __bf16 bf16x8;
typedef __attribute__((ext_vector_type(4))) float  f32x4;
typedef __attribute__((ext_vector_type(4))) unsigned int   u32x4;
typedef __attribute__((ext_vector_type(4))) unsigned short u16x4;
typedef __attribute__((ext_vector_type(8))) unsigned short u16x8;

typedef const __attribute__((address_space(1))) void* gas_t;
typedef __attribute__((address_space(3))) void* las_t;

static __device__ __forceinline__ unsigned short f2bf(float f) {
  return __builtin_bit_cast(unsigned short, __float2bfloat16(f));
}
static __device__ __forceinline__ float bf2f(unsigned short u) {
  return __bfloat162float(__builtin_bit_cast(__hip_bfloat16, u));
}

// ---------------------------------------------------------------------------
// Dtype probe. flags[0]=1 iff float inputs are f32 (else bf16).
// flags[1]=1 iff token_positions is int64 (else int32).
// Mechanism: reading consecutive bf16 pairs as f32 words yields exponent 0xFF
// (|hi bf16| in [1,2) with top mantissa bit set) ~9% of the time for N(0,1);
// true f32 N(0,1) words never have exponent 0xFF. int64 positions (<2^31)
// have all odd 32-bit words == 0.
// ---------------------------------------------------------------------------
__global__ __launch_bounds__(64) void probe_kernel(const unsigned int* __restrict__ x,
                                                   const int* __restrict__ pos,
                                                   int* __restrict__ flags) {
  const int lane = threadIdx.x;
  int bad = 0;
#pragma unroll
  for (int i = 0; i < 32; ++i) {
    const unsigned int u = x[lane * 32 + i];
    if (((u >> 23) & 0xFFu) == 0xFFu) bad++;
  }
  int zodd = 0;
#pragma unroll
  for (int i = 0; i < 4; ++i)
    if (pos[lane * 8 + 2 * i + 1] == 0) zodd++;
#pragma unroll
  for (int s = 1; s < 64; s <<= 1) {
    bad  += __shfl_xor(bad, s);
    zodd += __shfl_xor(zodd, s);
  }
  if (lane == 0) {
    flags[0] = (bad < 64) ? 1 : 0;    // 1 => f32 inputs
    flags[1] = (zodd >= 200) ? 1 : 0; // 1 => int64 positions
  }
}

// ---------------------------------------------------------------------------
// Canonicalize x,Wq,Wk,Wv,Wo into one contiguous bf16 buffer [x | Wq Wk Wv Wo].
// ---------------------------------------------------------------------------
__global__ __launch_bounds__(256) void conv_kernel(
    const void* __restrict__ x,
    const void* __restrict__ w0, const void* __restrict__ w1,
    const void* __restrict__ w2, const void* __restrict__ w3,
    unsigned short* __restrict__ dst, const int* __restrict__ flags) {
  const size_t e = ((size_t)blockIdx.x * 256 + threadIdx.x) * 8;
  const void* src;
  size_t off;
  if (e < XELEMS) { src = x; off = e; }
  else {
    const size_t r = e - XELEMS;
    const int wi = (int)(r >> 20);
    src = (wi == 0) ? w0 : (wi == 1) ? w1 : (wi == 2) ? w2 : w3;
    off = r & (WELEMS - 1);
  }
  if (flags[0]) {
    const float* s = (const float*)src + off;
    const f32x4 a = *(const f32x4*)(s);
    const f32x4 b = *(const f32x4*)(s + 4);
    u16x8 o8;
#pragma unroll
    for (int j = 0; j < 4; ++j) o8[j] = f2bf(a[j]);
#pragma unroll
    for (int j = 0; j < 4; ++j) o8[4 + j] = f2bf(b[j]);
    *(u16x8*)(dst + e) = o8;
  } else {
    *(u32x4*)(dst + e) = *(const u32x4*)((const unsigned short*)src + off);
  }
}

// ---------------------------------------------------------------------------
// Shared GEMM core: C[128x128] = A[128xK] * B[128xK]^T, K = DMODEL, bf16 MFMA.
// m97 structure: linear LDS, global_load_lds width 16, 2 barriers per K-step.
// ---------------------------------------------------------------------------
__device__ __forceinline__ void gemm_core(const unsigned short* __restrict__ Ag,
                                          const unsigned short* __restrict__ Bg,
                                          unsigned short* As, unsigned short* Bs,
                                          int bm, int bn, f32x4 acc[4][4]) {
  const int tid = threadIdx.x;
  const int lane = tid & 63;
  const int w  = tid >> 6;
  const int wm = w >> 1, wn = w & 1;
  const int c = lane & 15, g = lane >> 4;
  const int r0 = tid >> 2;
  const int s0 = (tid & 3) * 8;
  for (int k0 = 0; k0 < DMODEL; k0 += 32) {
    __syncthreads();
    __builtin_amdgcn_global_load_lds((gas_t)(Ag + (size_t)(bm + r0) * DMODEL + k0 + s0),
                                     (las_t)(As + tid * 8), 16, 0, 0);
    __builtin_amdgcn_global_load_lds((gas_t)(Ag + (size_t)(bm + r0 + 64) * DMODEL + k0 + s0),
                                     (las_t)(As + (tid + 256) * 8), 16, 0, 0);
    __builtin_amdgcn_global_load_lds((gas_t)(Bg + (size_t)(bn + r0) * DMODEL + k0 + s0),
                                     (las_t)(Bs + tid * 8), 16, 0, 0);
    __builtin_amdgcn_global_load_lds((gas_t)(Bg + (size_t)(bn + r0 + 64) * DMODEL + k0 + s0),
                                     (las_t)(Bs + (tid + 256) * 8), 16, 0, 0);
    __syncthreads();
    bf16x8 af[4], bfr[4];
#pragma unroll
    for (int m = 0; m < 4; ++m)
      af[m] = *(const bf16x8*)&As[(wm * 64 + m * 16 + c) * 32 + g * 8];
#pragma unroll
    for (int n = 0; n < 4; ++n)
      bfr[n] = *(const bf16x8*)&Bs[(wn * 64 + n * 16 + c) * 32 + g * 8];
#pragma unroll
    for (int m = 0; m < 4; ++m)
#pragma unroll
      for (int n = 0; n < 4; ++n)
        acc[m][n] = __builtin_amdgcn_mfma_f32_16x16x32_bf16(af[m], bfr[n], acc[m][n], 0, 0, 0);
  }
}

// ---------------------------------------------------------------------------
// QKV projection. grid = (32, 8, 3). Q,K stored [B,H,S,64]; V stored
// transposed [B,H,64,S].
// ---------------------------------------------------------------------------
__global__ __launch_bounds__(256) void qkv_gemm_kernel(
    const unsigned short* __restrict__ x,
    const unsigned short* __restrict__ Wq, const unsigned short* __restrict__ Wk,
    const unsigned short* __restrict__ Wv,
    unsigned short* __restrict__ qo, unsigned short* __restrict__ ko,
    unsigned short* __restrict__ vto) {
  __shared__ unsigned short As[128 * 32];
  __shared__ unsigned short Bs[128 * 32];
  const int z = blockIdx.z;
  const unsigned short* W = (z == 0) ? Wq : (z == 1) ? Wk : Wv;
  const int bm = blockIdx.x * 128, bn = blockIdx.y * 128;
  f32x4 acc[4][4];
#pragma unroll
  for (int m = 0; m < 4; ++m)
#pragma unroll
    for (int n = 0; n < 4; ++n)
#pragma unroll
      for (int j = 0; j < 4; ++j) acc[m][n][j] = 0.f;

  gemm_core(x, W, As, Bs, bm, bn, acc);

  const int tid = threadIdx.x, lane = tid & 63, w = tid >> 6;
  const int wm = w >> 1, wn = w & 1, c = lane & 15, g4 = lane >> 4;
#pragma unroll
  for (int m = 0; m < 4; ++m) {
#pragma unroll
    for (int n = 0; n < 4; ++n) {
      const int col = bn + wn * 64 + n * 16 + c;
      const int h = col >> 6, d = col & 63;
      const int row0 = bm + wm * 64 + m * 16 + g4 * 4;
      if (z == 2) {
        const int b = row0 >> 11, s0 = row0 & (SEQ - 1);
        u16x4 pk;
#pragma unroll
        for (int j = 0; j < 4; ++j) pk[j] = f2bf(acc[m][n][j]);
        *(u16x4*)&vto[((size_t)(b * NHEADS + h) * HDIM + d) * SEQ + s0] = pk;
      } else {
        unsigned short* dst = z ? ko : qo;
#pragma unroll
        for (int j = 0; j < 4; ++j) {
          const int row = row0 + j;
          const int b = row >> 11, s = row & (SEQ - 1);
          dst[((size_t)(b * NHEADS + h) * SEQ + s) * HDIM + d] = f2bf(acc[m][n][j]);
        }
      }
    }
  }
}

// ---------------------------------------------------------------------------
// Output projection: out = O[4096x1024] * Wo^T. Output dtype per flags[0].
// ---------------------------------------------------------------------------
__global__ __launch_bounds__(256) void out_gemm_kernel(
    const unsigned short* __restrict__ A, const unsigned short* __restrict__ Wo,
    void* __restrict__ outv, const int* __restrict__ flags) {
  __shared__ unsigned short As[128 * 32];
  __shared__ unsigned short Bs[128 * 32];
  const int bm = blockIdx.x * 128, bn = blockIdx.y * 128;
  f32x4 acc[4][4];
#pragma unroll
  for (int m = 0; m < 4; ++m)
#pragma unroll
    for (int n = 0; n < 4; ++n)
#pragma unroll
      for (int j = 0; j < 4; ++j) acc[m][n][j] = 0.f;

  gemm_core(A, Wo, As, Bs, bm, bn, acc);

  const int tid = threadIdx.x, lane = tid & 63, w = tid >> 6;
  const int wm = w >> 1, wn = w & 1, c = lane & 15, g4 = lane >> 4;
  const int f32o = flags[0];
  if (f32o) {
    float* out = (float*)outv;
#pragma unroll
    for (int m = 0; m < 4; ++m)
#pragma unroll
      for (int n = 0; n < 4; ++n) {
        const int col = bn + wn * 64 + n * 16 + c;
#pragma unroll
        for (int j = 0; j < 4; ++j) {
          const int row = bm + wm * 64 + m * 16 + g4 * 4 + j;
          out[(size_t)row * DMODEL + col] = acc[m][n][j];
        }
      }
  } else {
    unsigned short* out = (unsigned short*)outv;
#pragma unroll
    for (int m = 0; m < 4; ++m)
#pragma unroll
      for (int n = 0; n < 4; ++n) {
        const int col = bn + wn * 64 + n * 16 + c;
#pragma unroll
        for (int j = 0; j < 4; ++j) {
          const int row = bm + wm * 64 + m * 16 + g4 * 4 + j;
          out[(size_t)row * DMODEL + col] = f2bf(acc[m][n][j]);
        }
      }
  }
}

// ---------------------------------------------------------------------------
// RoPE in-place on Q and K ([B,H,S,64]).
// ---------------------------------------------------------------------------
__global__ __launch_bounds__(256) void rope_kernel(unsigned short* __restrict__ q,
                                                   unsigned short* __restrict__ k,
                                                   const int* __restrict__ pos,
                                                   const int* __restrict__ flags) {
  const int idx = blockIdx.x * 256 + threadIdx.x;
  const int tsel = idx >> 21;
  const int p = idx & ((1 << 21) - 1);
  const int j = p & 31;
  const int s = (p >> 5) & (SEQ - 1);
  const int bh = p >> 16;
  const int b = bh >> 4;
  unsigned short* base = tsel ? k : q;
  const int pidx = b * SEQ + s;
  const int pv = flags[1] ? pos[2 * pidx] : pos[pidx];
  const float freq = exp2f((float)j * -0.41524101186092026f);  // log2(10000)/32
  const float ang = (float)pv * freq;
  const float cs = cosf(ang);
  const float sn = sinf(ang);
  unsigned int* wp = (unsigned int*)base + ((p >> 5) * 32 + j);
  const unsigned int u = *wp;
  const float e = bf2f((unsigned short)(u & 0xffffu));
  const float o = bf2f((unsigned short)(u >> 16));
  *wp = (unsigned int)f2bf(e * cs - o * sn) | ((unsigned int)f2bf(e * sn + o * cs) << 16);
}

// ---------------------------------------------------------------------------
// Flash attention, causal. grid = (16, B*H). 4 waves x 32 q-rows, KV tiles 64.
// All masking uses finite -1e30 (NaN-proof by construction).
// ---------------------------------------------------------------------------
#define MNEG -1e30f
__global__ __launch_bounds__(256) void flash_kernel(
    const unsigned short* __restrict__ q, const unsigned short* __restrict__ k,
    const unsigned short* __restrict__ vt, unsigned short* __restrict__ o) {
  __shared__ unsigned short Qs[128 * 64];
  __shared__ unsigned short Ks[64 * 64];
  __shared__ unsigned short Vs[64 * 64];
  __shared__ unsigned short Ps[128 * 72];

  const int qt = (int)(gridDim.x - 1) - (int)blockIdx.x;
  const int bh = blockIdx.y;
  const int qbase = qt * 128;
  const int tid = threadIdx.x, lane = tid & 63, w = tid >> 6;
  const int c = lane & 15, g = lane >> 4;
  const int wq = w * 32;
  const size_t tb = (size_t)bh * SEQ * HDIM;

#pragma unroll
  for (int i = 0; i < 4; ++i) {
    const int t = tid + i * 256;
    const int r = t >> 3;
    const int sl = (t & 7) ^ (r & 7);
    __builtin_amdgcn_global_load_lds((gas_t)(q + tb + (size_t)(qbase + r) * HDIM + sl * 8),
                                     (las_t)(Qs + t * 8), 16, 0, 0);
  }
  __syncthreads();
  bf16x8 aq[2][2];
#pragma unroll
  for (int m = 0; m < 2; ++m)
#pragma unroll
    for (int kk = 0; kk < 2; ++kk) {
      const int r = wq + m * 16 + c;
      const int sl = (kk * 4 + g) ^ (r & 7);
      aq[m][kk] = *(const bf16x8*)&Qs[r * 64 + sl * 8];
    }

  f32x4 acco[2][4];
  float mrun[2][4], lrun[2][4];
#pragma unroll
  for (int m = 0; m < 2; ++m)
#pragma unroll
    for (int n = 0; n < 4; ++n)
#pragma unroll
      for (int j = 0; j < 4; ++j) acco[m][n][j] = 0.f;
#pragma unroll
  for (int m = 0; m < 2; ++m)
#pragma unroll
    for (int j = 0; j < 4; ++j) { mrun[m][j] = MNEG; lrun[m][j] = 0.f; }

  const int nkv = 2 * qt + 2;
  for (int kt = 0; kt < nkv; ++kt) {
    const int kvb = kt * 64;
    __syncthreads();
#pragma unroll
    for (int i = 0; i < 2; ++i) {
      const int t = tid + i * 256;
      const int r = t >> 3;
      const int sl = (t & 7) ^ (r & 7);
      __builtin_amdgcn_global_load_lds((gas_t)(k + tb + (size_t)(kvb + r) * HDIM + sl * 8),
                                       (las_t)(Ks + t * 8), 16, 0, 0);
      __builtin_amdgcn_global_load_lds((gas_t)(vt + tb + (size_t)r * SEQ + kvb + sl * 8),
                                       (las_t)(Vs + t * 8), 16, 0, 0);
    }
    __syncthreads();

    f32x4 accs[2][4];
#pragma unroll
    for (int m = 0; m < 2; ++m)
#pragma unroll
      for (int n = 0; n < 4; ++n)
#pragma unroll
        for (int j = 0; j < 4; ++j) accs[m][n][j] = 0.f;
#pragma unroll
    for (int kk = 0; kk < 2; ++kk) {
#pragma unroll
      for (int n = 0; n < 4; ++n) {
        const int r = n * 16 + c;
        const int sl = (kk * 4 + g) ^ (r & 7);
        const bf16x8 bk = *(const bf16x8*)&Ks[r * 64 + sl * 8];
#pragma unroll
        for (int m = 0; m < 2; ++m)
          accs[m][n] = __builtin_amdgcn_mfma_f32_16x16x32_bf16(aq[m][kk], bk, accs[m][n], 0, 0, 0);
      }
    }

    const bool domask = (kt >= 2 * qt);
#pragma unroll
    for (int m = 0; m < 2; ++m) {
      const int rowg0 = qbase + wq + m * 16 + g * 4;
#pragma unroll
      for (int n = 0; n < 4; ++n) {
        const int colg = kvb + n * 16 + c;
#pragma unroll
        for (int jj = 0; jj < 4; ++jj) {
          float v = accs[m][n][jj] * 0.125f;
          if (domask && colg > rowg0 + jj) v = MNEG;
          accs[m][n][jj] = v;
        }
      }
#pragma unroll
      for (int jj = 0; jj < 4; ++jj) {
        float rm = fmaxf(fmaxf(accs[m][0][jj], accs[m][1][jj]),
                         fmaxf(accs[m][2][jj], accs[m][3][jj]));
        rm = fmaxf(rm, __shfl_xor(rm, 1));
        rm = fmaxf(rm, __shfl_xor(rm, 2));
        rm = fmaxf(rm, __shfl_xor(rm, 4));
        rm = fmaxf(rm, __shfl_xor(rm, 8));
        const float mo = mrun[m][jj];
        const float mn = fmaxf(mo, rm);
        const float al = exp2f((mo - mn) * 1.4426950408889634f);
        float rs = 0.f;
#pragma unroll
        for (int n = 0; n < 4; ++n) {
          const float pv = exp2f((accs[m][n][jj] - mn) * 1.4426950408889634f);
          accs[m][n][jj] = pv;
          rs += pv;
        }
        rs += __shfl_xor(rs, 1);
        rs += __shfl_xor(rs, 2);
        rs += __shfl_xor(rs, 4);
        rs += __shfl_xor(rs, 8);
        lrun[m][jj] = lrun[m][jj] * al + rs;
        mrun[m][jj] = mn;
#pragma unroll
        for (int n = 0; n < 4; ++n) acco[m][n][jj] *= al;
      }
#pragma unroll
      for (int n = 0; n < 4; ++n)
#pragma unroll
        for (int jj = 0; jj < 4; ++jj)
          Ps[(wq + m * 16 + g * 4 + jj) * 72 + n * 16 + c] = f2bf(accs[m][n][jj]);
    }

#pragma unroll
    for (int kk = 0; kk < 2; ++kk) {
      bf16x8 pa[2];
#pragma unroll
      for (int m = 0; m < 2; ++m)
        pa[m] = *(const bf16x8*)&Ps[(wq + m * 16 + c) * 72 + kk * 32 + g * 8];
#pragma unroll
      for (int n = 0; n < 4; ++n) {
        const int r = n * 16 + c;
        const int sl = (kk * 4 + g) ^ (r & 7);
        const bf16x8 bv = *(const bf16x8*)&Vs[r * 64 + sl * 8];
#pragma unroll
        for (int m = 0; m < 2; ++m)
          acco[m][n] = __builtin_amdgcn_mfma_f32_16x16x32_bf16(pa[m], bv, acco[m][n], 0, 0, 0);
      }
    }
  }

  const int b = bh >> 4, h = bh & 15;
#pragma unroll
  for (int m = 0; m < 2; ++m)
#pragma unroll
    for (int n = 0; n < 4; ++n)
#pragma unroll
      for (int jj = 0; jj < 4; ++jj) {
        const int rowg = qbase + wq + m * 16 + g * 4 + jj;
        const int col = h * 64 + n * 16 + c;
        o[(size_t)(b * SEQ + rowg) * DMODEL + col] =
            f2bf(acco[m][n][jj] / fmaxf(lrun[m][jj], 1e-20f));
      }
}

// ---------------------------------------------------------------------------
extern "C" void kernel_launch(void* const* d_in, const int* in_sizes, int n_in,
                              void* d_out, int out_size, void* d_ws, size_t ws_size,
                              hipStream_t stream) {
  (void)in_sizes; (void)n_in; (void)out_size; (void)ws_size;
  const size_t MB = (size_t)1 << 20;
  char* ws = (char*)d_ws;
  unsigned short* xb  = (unsigned short*)(ws);            // 8 MB (reused as ow)
  unsigned short* Wqb = (unsigned short*)(ws + 8 * MB);   // 2 MB each
  unsigned short* Wkb = (unsigned short*)(ws + 10 * MB);
  unsigned short* Wvb = (unsigned short*)(ws + 12 * MB);
  unsigned short* Wob = (unsigned short*)(ws + 14 * MB);
  unsigned short* qw  = (unsigned short*)(ws + 16 * MB);  // 8 MB
  unsigned short* kw  = (unsigned short*)(ws + 24 * MB);  // 8 MB
  unsigned short* vtw = (unsigned short*)(ws + 32 * MB);  // 8 MB
  int* flags          = (int*)(ws + 40 * MB);
  unsigned short* ow  = xb;  // x dead after qkv_gemm

  const dim3 blk(256);
  probe_kernel<<<1, 64, 0, stream>>>((const unsigned int*)d_in[0], (const int*)d_in[5], flags);
  conv_kernel<<<4096, blk, 0, stream>>>(d_in[0], d_in[1], d_in[2], d_in[3], d_in[4], xb, flags);
  qkv_gemm_kernel<<<dim3(32, 8, 3), blk, 0, stream>>>(xb, Wqb, Wkb, Wvb, qw, kw, vtw);
  rope_kernel<<<16384, blk, 0, stream>>>(qw, kw, (const int*)d_in[5], flags);
  flash_kernel<<<dim3(16, 32), blk, 0, stream>>>(qw, kw, vtw, ow);
  out_gemm_kernel<<<dim3(32, 8), blk, 0, stream>>>(ow, Wob, d_out, flags);
}

// Round 3
// 154.304 us; speedup vs baseline: 1.4446x; 1.4446x over previous
//
#include <hip/hip_runtime.h>
#include <hip/hip_bf16.h>

#define DMODEL 1024
#define NHEADS 16
#define HDIM   64
#define BATCH  2
#define SEQ    2048
#define XELEMS ((size_t)BATCH * SEQ * DMODEL)   // 4,194,304
#define WELEMS ((size_t)DMODEL * DMODEL)        // 1,048,576

typedef __attribute__((ext_vector_type(8))) __bf16 bf16x8;
typedef __attribute__((ext_vector_type(4))) float  f32x4;
typedef __attribute__((ext_vector_type(4))) unsigned int   u32x4;
typedef __attribute__((ext_vector_type(4))) unsigned short u16x4;
typedef __attribute__((ext_vector_type(8))) unsigned short u16x8;

typedef const __attribute__((address_space(1))) void* gas_t;
typedef __attribute__((address_space(3))) void* las_t;

static __device__ __forceinline__ unsigned short f2bf(float f) {
  return __builtin_bit_cast(unsigned short, __float2bfloat16(f));
}
static __device__ __forceinline__ float bf2f(unsigned short u) {
  return __bfloat162float(__builtin_bit_cast(__hip_bfloat16, u));
}

// ---------------------------------------------------------------------------
// Dtype probe. flags[0]=1 iff float inputs are f32 (else bf16).
// flags[1]=1 iff token_positions is int64 (else int32).
// ---------------------------------------------------------------------------
__global__ __launch_bounds__(64) void probe_kernel(const unsigned int* __restrict__ x,
                                                   const int* __restrict__ pos,
                                                   int* __restrict__ flags) {
  const int lane = threadIdx.x;
  int bad = 0;
#pragma unroll
  for (int i = 0; i < 32; ++i) {
    const unsigned int u = x[lane * 32 + i];
    if (((u >> 23) & 0xFFu) == 0xFFu) bad++;
  }
  int zodd = 0;
#pragma unroll
  for (int i = 0; i < 4; ++i)
    if (pos[lane * 8 + 2 * i + 1] == 0) zodd++;
#pragma unroll
  for (int s = 1; s < 64; s <<= 1) {
    bad  += __shfl_xor(bad, s);
    zodd += __shfl_xor(zodd, s);
  }
  if (lane == 0) {
    flags[0] = (bad < 64) ? 1 : 0;    // 1 => f32 inputs
    flags[1] = (zodd >= 200) ? 1 : 0; // 1 => int64 positions
  }
}

// ---------------------------------------------------------------------------
// Canonicalize x,Wq,Wk,Wv,Wo into one contiguous bf16 buffer [x | Wq Wk Wv Wo].
// ---------------------------------------------------------------------------
__global__ __launch_bounds__(256) void conv_kernel(
    const void* __restrict__ x,
    const void* __restrict__ w0, const void* __restrict__ w1,
    const void* __restrict__ w2, const void* __restrict__ w3,
    unsigned short* __restrict__ dst, const int* __restrict__ flags) {
  const size_t e = ((size_t)blockIdx.x * 256 + threadIdx.x) * 8;
  const void* src;
  size_t off;
  if (e < XELEMS) { src = x; off = e; }
  else {
    const size_t r = e - XELEMS;
    const int wi = (int)(r >> 20);
    src = (wi == 0) ? w0 : (wi == 1) ? w1 : (wi == 2) ? w2 : w3;
    off = r & (WELEMS - 1);
  }
  if (flags[0]) {
    const float* s = (const float*)src + off;
    const f32x4 a = *(const f32x4*)(s);
    const f32x4 b = *(const f32x4*)(s + 4);
    u16x8 o8;
#pragma unroll
    for (int j = 0; j < 4; ++j) o8[j] = f2bf(a[j]);
#pragma unroll
    for (int j = 0; j < 4; ++j) o8[4 + j] = f2bf(b[j]);
    *(u16x8*)(dst + e) = o8;
  } else {
    *(u32x4*)(dst + e) = *(const u32x4*)((const unsigned short*)src + off);
  }
}

// ---------------------------------------------------------------------------
// Shared GEMM core: C[128x128] = A[128xK] * B[128xK]^T, K = DMODEL, bf16 MFMA.
// ---------------------------------------------------------------------------
__device__ __forceinline__ void gemm_core(const unsigned short* __restrict__ Ag,
                                          const unsigned short* __restrict__ Bg,
                                          unsigned short* As, unsigned short* Bs,
                                          int bm, int bn, f32x4 acc[4][4]) {
  const int tid = threadIdx.x;
  const int lane = tid & 63;
  const int w  = tid >> 6;
  const int wm = w >> 1, wn = w & 1;
  const int c = lane & 15, g = lane >> 4;
  const int r0 = tid >> 2;
  const int s0 = (tid & 3) * 8;
  for (int k0 = 0; k0 < DMODEL; k0 += 32) {
    __syncthreads();
    __builtin_amdgcn_global_load_lds((gas_t)(Ag + (size_t)(bm + r0) * DMODEL + k0 + s0),
                                     (las_t)(As + tid * 8), 16, 0, 0);
    __builtin_amdgcn_global_load_lds((gas_t)(Ag + (size_t)(bm + r0 + 64) * DMODEL + k0 + s0),
                                     (las_t)(As + (tid + 256) * 8), 16, 0, 0);
    __builtin_amdgcn_global_load_lds((gas_t)(Bg + (size_t)(bn + r0) * DMODEL + k0 + s0),
                                     (las_t)(Bs + tid * 8), 16, 0, 0);
    __builtin_amdgcn_global_load_lds((gas_t)(Bg + (size_t)(bn + r0 + 64) * DMODEL + k0 + s0),
                                     (las_t)(Bs + (tid + 256) * 8), 16, 0, 0);
    __syncthreads();
    bf16x8 af[4], bfr[4];
#pragma unroll
    for (int m = 0; m < 4; ++m)
      af[m] = *(const bf16x8*)&As[(wm * 64 + m * 16 + c) * 32 + g * 8];
#pragma unroll
    for (int n = 0; n < 4; ++n)
      bfr[n] = *(const bf16x8*)&Bs[(wn * 64 + n * 16 + c) * 32 + g * 8];
#pragma unroll
    for (int m = 0; m < 4; ++m)
#pragma unroll
      for (int n = 0; n < 4; ++n)
        acc[m][n] = __builtin_amdgcn_mfma_f32_16x16x32_bf16(af[m], bfr[n], acc[m][n], 0, 0, 0);
  }
}

// ---------------------------------------------------------------------------
// QKV projection. grid = (32, 8, 3). Q,K stored [B,H,S,64]; V stored
// transposed [B,H,64,S].
// ---------------------------------------------------------------------------
__global__ __launch_bounds__(256) void qkv_gemm_kernel(
    const unsigned short* __restrict__ x,
    const unsigned short* __restrict__ Wq, const unsigned short* __restrict__ Wk,
    const unsigned short* __restrict__ Wv,
    unsigned short* __restrict__ qo, unsigned short* __restrict__ ko,
    unsigned short* __restrict__ vto) {
  __shared__ unsigned short As[128 * 32];
  __shared__ unsigned short Bs[128 * 32];
  const int z = blockIdx.z;
  const unsigned short* W = (z == 0) ? Wq : (z == 1) ? Wk : Wv;
  const int bm = blockIdx.x * 128, bn = blockIdx.y * 128;
  f32x4 acc[4][4];
#pragma unroll
  for (int m = 0; m < 4; ++m)
#pragma unroll
    for (int n = 0; n < 4; ++n)
#pragma unroll
      for (int j = 0; j < 4; ++j) acc[m][n][j] = 0.f;

  gemm_core(x, W, As, Bs, bm, bn, acc);

  const int tid = threadIdx.x, lane = tid & 63, w = tid >> 6;
  const int wm = w >> 1, wn = w & 1, c = lane & 15, g4 = lane >> 4;
#pragma unroll
  for (int m = 0; m < 4; ++m) {
#pragma unroll
    for (int n = 0; n < 4; ++n) {
      const int col = bn + wn * 64 + n * 16 + c;
      const int h = col >> 6, d = col & 63;
      const int row0 = bm + wm * 64 + m * 16 + g4 * 4;
      if (z == 2) {
        const int b = row0 >> 11, s0 = row0 & (SEQ - 1);
        u16x4 pk;
#pragma unroll
        for (int j = 0; j < 4; ++j) pk[j] = f2bf(acc[m][n][j]);
        *(u16x4*)&vto[((size_t)(b * NHEADS + h) * HDIM + d) * SEQ + s0] = pk;
      } else {
        unsigned short* dst = z ? ko : qo;
#pragma unroll
        for (int j = 0; j < 4; ++j) {
          const int row = row0 + j;
          const int b = row >> 11, s = row & (SEQ - 1);
          dst[((size_t)(b * NHEADS + h) * SEQ + s) * HDIM + d] = f2bf(acc[m][n][j]);
        }
      }
    }
  }
}

// ---------------------------------------------------------------------------
// Output projection: out = O[4096x1024] * Wo^T. Output dtype per flags[0].
// ---------------------------------------------------------------------------
__global__ __launch_bounds__(256) void out_gemm_kernel(
    const unsigned short* __restrict__ A, const unsigned short* __restrict__ Wo,
    void* __restrict__ outv, const int* __restrict__ flags) {
  __shared__ unsigned short As[128 * 32];
  __shared__ unsigned short Bs[128 * 32];
  const int bm = blockIdx.x * 128, bn = blockIdx.y * 128;
  f32x4 acc[4][4];
#pragma unroll
  for (int m = 0; m < 4; ++m)
#pragma unroll
    for (int n = 0; n < 4; ++n)
#pragma unroll
      for (int j = 0; j < 4; ++j) acc[m][n][j] = 0.f;

  gemm_core(A, Wo, As, Bs, bm, bn, acc);

  const int tid = threadIdx.x, lane = tid & 63, w = tid >> 6;
  const int wm = w >> 1, wn = w & 1, c = lane & 15, g4 = lane >> 4;
  const int f32o = flags[0];
  if (f32o) {
    float* out = (float*)outv;
#pragma unroll
    for (int m = 0; m < 4; ++m)
#pragma unroll
      for (int n = 0; n < 4; ++n) {
        const int col = bn + wn * 64 + n * 16 + c;
#pragma unroll
        for (int j = 0; j < 4; ++j) {
          const int row = bm + wm * 64 + m * 16 + g4 * 4 + j;
          out[(size_t)row * DMODEL + col] = acc[m][n][j];
        }
      }
  } else {
    unsigned short* out = (unsigned short*)outv;
#pragma unroll
    for (int m = 0; m < 4; ++m)
#pragma unroll
      for (int n = 0; n < 4; ++n) {
        const int col = bn + wn * 64 + n * 16 + c;
#pragma unroll
        for (int j = 0; j < 4; ++j) {
          const int row = bm + wm * 64 + m * 16 + g4 * 4 + j;
          out[(size_t)row * DMODEL + col] = f2bf(acc[m][n][j]);
        }
      }
  }
}

// ---------------------------------------------------------------------------
// RoPE in-place on Q and K ([B,H,S,64]).
// ---------------------------------------------------------------------------
__global__ __launch_bounds__(256) void rope_kernel(unsigned short* __restrict__ q,
                                                   unsigned short* __restrict__ k,
                                                   const int* __restrict__ pos,
                                                   const int* __restrict__ flags) {
  const int idx = blockIdx.x * 256 + threadIdx.x;
  const int tsel = idx >> 21;
  const int p = idx & ((1 << 21) - 1);
  const int j = p & 31;
  const int s = (p >> 5) & (SEQ - 1);
  const int bh = p >> 16;
  const int b = bh >> 4;
  unsigned short* base = tsel ? k : q;
  const int pidx = b * SEQ + s;
  const int pv = flags[1] ? pos[2 * pidx] : pos[pidx];
  const float freq = exp2f((float)j * -0.41524101186092026f);  // log2(10000)/32
  const float ang = (float)pv * freq;
  const float cs = cosf(ang);
  const float sn = sinf(ang);
  unsigned int* wp = (unsigned int*)base + ((p >> 5) * 32 + j);
  const unsigned int u = *wp;
  const float e = bf2f((unsigned short)(u & 0xffffu));
  const float o = bf2f((unsigned short)(u >> 16));
  *wp = (unsigned int)f2bf(e * cs - o * sn) | ((unsigned int)f2bf(e * sn + o * cs) << 16);
}

// ---------------------------------------------------------------------------
// Flash attention v2, causal. 1D grid of 1024 blocks, work-sorted descending.
// QBLK=64 (4 waves x 16 q-rows), KVBLK=64, double-buffered K/V staging:
// next tile's global_load_lds issued BEFORE compute so the single end-of-tile
// __syncthreads (which drains vmcnt) finds the loads already landed.
// ---------------------------------------------------------------------------
#define MNEG -1e30f
#define QBLK 64
__global__ __launch_bounds__(256) void flash_kernel(
    const unsigned short* __restrict__ q, const unsigned short* __restrict__ k,
    const unsigned short* __restrict__ vt, unsigned short* __restrict__ o) {
  __shared__ unsigned short Qs[64 * 64];      //  8 KB (swizzled)
  __shared__ unsigned short Ks[2][64 * 64];   // 16 KB double-buffered
  __shared__ unsigned short Vs[2][64 * 64];   // 16 KB double-buffered
  __shared__ unsigned short Ps[64 * 72];      //  9 KB (padded stride 72)

  const int wg = blockIdx.x;                  // 0..1023, sorted big-first
  const int qt = (SEQ / QBLK - 1) - (wg >> 5);
  const int bh = wg & 31;
  const int qbase = qt * QBLK;
  const int tid = threadIdx.x, lane = tid & 63, w = tid >> 6;
  const int c = lane & 15, g = lane >> 4;
  const int wq = w * 16;
  const size_t tb = (size_t)bh * SEQ * HDIM;

  // ---- stage Q tile (64 rows x 128B) + K/V tile 0 ----
#pragma unroll
  for (int i = 0; i < 2; ++i) {
    const int t = tid + i * 256;
    const int r = t >> 3;
    const int sl = (t & 7) ^ (r & 7);
    __builtin_amdgcn_global_load_lds((gas_t)(q + tb + (size_t)(qbase + r) * HDIM + sl * 8),
                                     (las_t)(Qs + t * 8), 16, 0, 0);
    __builtin_amdgcn_global_load_lds((gas_t)(k + tb + (size_t)r * HDIM + sl * 8),
                                     (las_t)(Ks[0] + t * 8), 16, 0, 0);
    __builtin_amdgcn_global_load_lds((gas_t)(vt + tb + (size_t)r * SEQ + sl * 8),
                                     (las_t)(Vs[0] + t * 8), 16, 0, 0);
  }
  __syncthreads();

  bf16x8 aq[2];
#pragma unroll
  for (int kk = 0; kk < 2; ++kk) {
    const int r = wq + c;
    const int sl = (kk * 4 + g) ^ (r & 7);
    aq[kk] = *(const bf16x8*)&Qs[r * 64 + sl * 8];
  }

  f32x4 acco[4];
  float mrun[4], lrun[4];
#pragma unroll
  for (int n = 0; n < 4; ++n)
#pragma unroll
    for (int j = 0; j < 4; ++j) acco[n][j] = 0.f;
#pragma unroll
  for (int j = 0; j < 4; ++j) { mrun[j] = MNEG; lrun[j] = 0.f; }

  const int nkv = qt + 1;
  for (int kt = 0; kt < nkv; ++kt) {
    const int p = kt & 1;
    // ---- prefetch next K/V tile into other buffer (overlaps with compute) ----
    if (kt + 1 < nkv) {
      const int kvb1 = (kt + 1) * 64;
#pragma unroll
      for (int i = 0; i < 2; ++i) {
        const int t = tid + i * 256;
        const int r = t >> 3;
        const int sl = (t & 7) ^ (r & 7);
        __builtin_amdgcn_global_load_lds((gas_t)(k + tb + (size_t)(kvb1 + r) * HDIM + sl * 8),
                                         (las_t)(Ks[p ^ 1] + t * 8), 16, 0, 0);
        __builtin_amdgcn_global_load_lds((gas_t)(vt + tb + (size_t)r * SEQ + kvb1 + sl * 8),
                                         (las_t)(Vs[p ^ 1] + t * 8), 16, 0, 0);
      }
    }

    // ---- S = Q K^T on current buffer ----
    f32x4 accs[4];
#pragma unroll
    for (int n = 0; n < 4; ++n)
#pragma unroll
      for (int j = 0; j < 4; ++j) accs[n][j] = 0.f;
#pragma unroll
    for (int kk = 0; kk < 2; ++kk) {
#pragma unroll
      for (int n = 0; n < 4; ++n) {
        const int r = n * 16 + c;
        const int sl = (kk * 4 + g) ^ (r & 7);
        const bf16x8 bk = *(const bf16x8*)&Ks[p][r * 64 + sl * 8];
        accs[n] = __builtin_amdgcn_mfma_f32_16x16x32_bf16(aq[kk], bk, accs[n], 0, 0, 0);
      }
    }

    // ---- mask + online softmax (rows g*4+jj, cols spread over c and n) ----
    const int kvb = kt * 64;
    const bool domask = (kt == qt);
    const int rowg0 = qbase + wq + g * 4;
#pragma unroll
    for (int n = 0; n < 4; ++n) {
      const int colg = kvb + n * 16 + c;
#pragma unroll
      for (int jj = 0; jj < 4; ++jj) {
        float v = accs[n][jj] * 0.125f;
        if (domask && colg > rowg0 + jj) v = MNEG;
        accs[n][jj] = v;
      }
    }
#pragma unroll
    for (int jj = 0; jj < 4; ++jj) {
      float rm = fmaxf(fmaxf(accs[0][jj], accs[1][jj]),
                       fmaxf(accs[2][jj], accs[3][jj]));
      rm = fmaxf(rm, __shfl_xor(rm, 1));
      rm = fmaxf(rm, __shfl_xor(rm, 2));
      rm = fmaxf(rm, __shfl_xor(rm, 4));
      rm = fmaxf(rm, __shfl_xor(rm, 8));
      const float mo = mrun[jj];
      const float mn = fmaxf(mo, rm);
      const float al = exp2f((mo - mn) * 1.4426950408889634f);
      float rs = 0.f;
#pragma unroll
      for (int n = 0; n < 4; ++n) {
        const float pv = exp2f((accs[n][jj] - mn) * 1.4426950408889634f);
        accs[n][jj] = pv;
        rs += pv;
      }
      rs += __shfl_xor(rs, 1);
      rs += __shfl_xor(rs, 2);
      rs += __shfl_xor(rs, 4);
      rs += __shfl_xor(rs, 8);
      lrun[jj] = lrun[jj] * al + rs;
      mrun[jj] = mn;
#pragma unroll
      for (int n = 0; n < 4; ++n) acco[n][jj] *= al;
    }
    // ---- P through wave-private LDS to reach MFMA A-layout ----
#pragma unroll
    for (int n = 0; n < 4; ++n)
#pragma unroll
      for (int jj = 0; jj < 4; ++jj)
        Ps[(wq + g * 4 + jj) * 72 + n * 16 + c] = f2bf(accs[n][jj]);

    // ---- O += P V ----
#pragma unroll
    for (int kk = 0; kk < 2; ++kk) {
      const bf16x8 pa = *(const bf16x8*)&Ps[(wq + c) * 72 + kk * 32 + g * 8];
#pragma unroll
      for (int n = 0; n < 4; ++n) {
        const int r = n * 16 + c;
        const int sl = (kk * 4 + g) ^ (r & 7);
        const bf16x8 bv = *(const bf16x8*)&Vs[p][r * 64 + sl * 8];
        acco[n] = __builtin_amdgcn_mfma_f32_16x16x32_bf16(pa, bv, acco[n], 0, 0, 0);
      }
    }
    __syncthreads();  // publish prefetched buffer; all waves done with buf p
  }

  // ---- epilogue: O / l, store to [B,S,H*64] ----
  const int b = bh >> 4, h = bh & 15;
#pragma unroll
  for (int n = 0; n < 4; ++n)
#pragma unroll
    for (int jj = 0; jj < 4; ++jj) {
      const int rowg = qbase + wq + g * 4 + jj;
      const int col = h * 64 + n * 16 + c;
      o[(size_t)(b * SEQ + rowg) * DMODEL + col] =
          f2bf(acco[n][jj] / fmaxf(lrun[jj], 1e-20f));
    }
}

// ---------------------------------------------------------------------------
extern "C" void kernel_launch(void* const* d_in, const int* in_sizes, int n_in,
                              void* d_out, int out_size, void* d_ws, size_t ws_size,
                              hipStream_t stream) {
  (void)in_sizes; (void)n_in; (void)out_size; (void)ws_size;
  const size_t MB = (size_t)1 << 20;
  char* ws = (char*)d_ws;
  unsigned short* xb  = (unsigned short*)(ws);            // 8 MB (reused as ow)
  unsigned short* Wqb = (unsigned short*)(ws + 8 * MB);   // 2 MB each
  unsigned short* Wkb = (unsigned short*)(ws + 10 * MB);
  unsigned short* Wvb = (unsigned short*)(ws + 12 * MB);
  unsigned short* Wob = (unsigned short*)(ws + 14 * MB);
  unsigned short* qw  = (unsigned short*)(ws + 16 * MB);  // 8 MB
  unsigned short* kw  = (unsigned short*)(ws + 24 * MB);  // 8 MB
  unsigned short* vtw = (unsigned short*)(ws + 32 * MB);  // 8 MB
  int* flags          = (int*)(ws + 40 * MB);
  unsigned short* ow  = xb;  // x dead after qkv_gemm

  const dim3 blk(256);
  probe_kernel<<<1, 64, 0, stream>>>((const unsigned int*)d_in[0], (const int*)d_in[5], flags);
  conv_kernel<<<4096, blk, 0, stream>>>(d_in[0], d_in[1], d_in[2], d_in[3], d_in[4], xb, flags);
  qkv_gemm_kernel<<<dim3(32, 8, 3), blk, 0, stream>>>(xb, Wqb, Wkb, Wvb, qw, kw, vtw);
  rope_kernel<<<16384, blk, 0, stream>>>(qw, kw, (const int*)d_in[5], flags);
  flash_kernel<<<dim3(1024), blk, 0, stream>>>(qw, kw, vtw, ow);
  out_gemm_kernel<<<dim3(32, 8), blk, 0, stream>>>(ow, Wob, d_out, flags);
}

// Round 4
// 134.054 us; speedup vs baseline: 1.6628x; 1.1511x over previous
//
#include <hip/hip_runtime.h>
#include <hip/hip_bf16.h>

#define DMODEL 1024
#define NHEADS 16
#define HDIM   64
#define BATCH  2
#define SEQ    2048
#define XELEMS ((size_t)BATCH * SEQ * DMODEL)   // 4,194,304
#define WELEMS ((size_t)DMODEL * DMODEL)        // 1,048,576

typedef __attribute__((ext_vector_type(8))) __bf16 bf16x8;
typedef __attribute__((ext_vector_type(4))) float  f32x4;
typedef __attribute__((ext_vector_type(4))) unsigned int   u32x4;
typedef __attribute__((ext_vector_type(4))) unsigned short u16x4;
typedef __attribute__((ext_vector_type(8))) unsigned short u16x8;

typedef const __attribute__((address_space(1))) void* gas_t;
typedef __attribute__((address_space(3))) void* las_t;

static __device__ __forceinline__ unsigned short f2bf(float f) {
  return __builtin_bit_cast(unsigned short, __float2bfloat16(f));
}
static __device__ __forceinline__ float bf2f(unsigned short u) {
  return __bfloat162float(__builtin_bit_cast(__hip_bfloat16, u));
}

// ---------------------------------------------------------------------------
// Dtype probe. flags[0]=1 iff float inputs are f32 (else bf16).
// flags[1]=1 iff token_positions is int64 (else int32).
// ---------------------------------------------------------------------------
__global__ __launch_bounds__(64) void probe_kernel(const unsigned int* __restrict__ x,
                                                   const int* __restrict__ pos,
                                                   int* __restrict__ flags) {
  const int lane = threadIdx.x;
  int bad = 0;
#pragma unroll
  for (int i = 0; i < 32; ++i) {
    const unsigned int u = x[lane * 32 + i];
    if (((u >> 23) & 0xFFu) == 0xFFu) bad++;
  }
  int zodd = 0;
#pragma unroll
  for (int i = 0; i < 4; ++i)
    if (pos[lane * 8 + 2 * i + 1] == 0) zodd++;
#pragma unroll
  for (int s = 1; s < 64; s <<= 1) {
    bad  += __shfl_xor(bad, s);
    zodd += __shfl_xor(zodd, s);
  }
  if (lane == 0) {
    flags[0] = (bad < 64) ? 1 : 0;    // 1 => f32 inputs
    flags[1] = (zodd >= 200) ? 1 : 0; // 1 => int64 positions
  }
}

// ---------------------------------------------------------------------------
// Canonicalize x,Wq,Wk,Wv,Wo into one contiguous bf16 buffer [x | Wq Wk Wv Wo].
// ---------------------------------------------------------------------------
__global__ __launch_bounds__(256) void conv_kernel(
    const void* __restrict__ x,
    const void* __restrict__ w0, const void* __restrict__ w1,
    const void* __restrict__ w2, const void* __restrict__ w3,
    unsigned short* __restrict__ dst, const int* __restrict__ flags) {
  const size_t e = ((size_t)blockIdx.x * 256 + threadIdx.x) * 8;
  const void* src;
  size_t off;
  if (e < XELEMS) { src = x; off = e; }
  else {
    const size_t r = e - XELEMS;
    const int wi = (int)(r >> 20);
    src = (wi == 0) ? w0 : (wi == 1) ? w1 : (wi == 2) ? w2 : w3;
    off = r & (WELEMS - 1);
  }
  if (flags[0]) {
    const float* s = (const float*)src + off;
    const f32x4 a = *(const f32x4*)(s);
    const f32x4 b = *(const f32x4*)(s + 4);
    u16x8 o8;
#pragma unroll
    for (int j = 0; j < 4; ++j) o8[j] = f2bf(a[j]);
#pragma unroll
    for (int j = 0; j < 4; ++j) o8[4 + j] = f2bf(b[j]);
    *(u16x8*)(dst + e) = o8;
  } else {
    *(u32x4*)(dst + e) = *(const u32x4*)((const unsigned short*)src + off);
  }
}

// ---------------------------------------------------------------------------
// Shared GEMM core: C[128x128] = A[128xK] * B[128xK]^T, K = DMODEL, bf16 MFMA.
// ---------------------------------------------------------------------------
__device__ __forceinline__ void gemm_core(const unsigned short* __restrict__ Ag,
                                          const unsigned short* __restrict__ Bg,
                                          unsigned short* As, unsigned short* Bs,
                                          int bm, int bn, f32x4 acc[4][4]) {
  const int tid = threadIdx.x;
  const int lane = tid & 63;
  const int w  = tid >> 6;
  const int wm = w >> 1, wn = w & 1;
  const int c = lane & 15, g = lane >> 4;
  const int r0 = tid >> 2;
  const int s0 = (tid & 3) * 8;
  for (int k0 = 0; k0 < DMODEL; k0 += 32) {
    __syncthreads();
    __builtin_amdgcn_global_load_lds((gas_t)(Ag + (size_t)(bm + r0) * DMODEL + k0 + s0),
                                     (las_t)(As + tid * 8), 16, 0, 0);
    __builtin_amdgcn_global_load_lds((gas_t)(Ag + (size_t)(bm + r0 + 64) * DMODEL + k0 + s0),
                                     (las_t)(As + (tid + 256) * 8), 16, 0, 0);
    __builtin_amdgcn_global_load_lds((gas_t)(Bg + (size_t)(bn + r0) * DMODEL + k0 + s0),
                                     (las_t)(Bs + tid * 8), 16, 0, 0);
    __builtin_amdgcn_global_load_lds((gas_t)(Bg + (size_t)(bn + r0 + 64) * DMODEL + k0 + s0),
                                     (las_t)(Bs + (tid + 256) * 8), 16, 0, 0);
    __syncthreads();
    bf16x8 af[4], bfr[4];
#pragma unroll
    for (int m = 0; m < 4; ++m)
      af[m] = *(const bf16x8*)&As[(wm * 64 + m * 16 + c) * 32 + g * 8];
#pragma unroll
    for (int n = 0; n < 4; ++n)
      bfr[n] = *(const bf16x8*)&Bs[(wn * 64 + n * 16 + c) * 32 + g * 8];
#pragma unroll
    for (int m = 0; m < 4; ++m)
#pragma unroll
      for (int n = 0; n < 4; ++n)
        acc[m][n] = __builtin_amdgcn_mfma_f32_16x16x32_bf16(af[m], bfr[n], acc[m][n], 0, 0, 0);
  }
}

// ---------------------------------------------------------------------------
// QKV projection. grid = (32, 8, 3). Q,K stored [B,H,S,64]; V stored
// transposed [B,H,64,S].
// ---------------------------------------------------------------------------
__global__ __launch_bounds__(256) void qkv_gemm_kernel(
    const unsigned short* __restrict__ x,
    const unsigned short* __restrict__ Wq, const unsigned short* __restrict__ Wk,
    const unsigned short* __restrict__ Wv,
    unsigned short* __restrict__ qo, unsigned short* __restrict__ ko,
    unsigned short* __restrict__ vto) {
  __shared__ unsigned short As[128 * 32];
  __shared__ unsigned short Bs[128 * 32];
  const int z = blockIdx.z;
  const unsigned short* W = (z == 0) ? Wq : (z == 1) ? Wk : Wv;
  const int bm = blockIdx.x * 128, bn = blockIdx.y * 128;
  f32x4 acc[4][4];
#pragma unroll
  for (int m = 0; m < 4; ++m)
#pragma unroll
    for (int n = 0; n < 4; ++n)
#pragma unroll
      for (int j = 0; j < 4; ++j) acc[m][n][j] = 0.f;

  gemm_core(x, W, As, Bs, bm, bn, acc);

  const int tid = threadIdx.x, lane = tid & 63, w = tid >> 6;
  const int wm = w >> 1, wn = w & 1, c = lane & 15, g4 = lane >> 4;
#pragma unroll
  for (int m = 0; m < 4; ++m) {
#pragma unroll
    for (int n = 0; n < 4; ++n) {
      const int col = bn + wn * 64 + n * 16 + c;
      const int h = col >> 6, d = col & 63;
      const int row0 = bm + wm * 64 + m * 16 + g4 * 4;
      if (z == 2) {
        const int b = row0 >> 11, s0 = row0 & (SEQ - 1);
        u16x4 pk;
#pragma unroll
        for (int j = 0; j < 4; ++j) pk[j] = f2bf(acc[m][n][j]);
        *(u16x4*)&vto[((size_t)(b * NHEADS + h) * HDIM + d) * SEQ + s0] = pk;
      } else {
        unsigned short* dst = z ? ko : qo;
#pragma unroll
        for (int j = 0; j < 4; ++j) {
          const int row = row0 + j;
          const int b = row >> 11, s = row & (SEQ - 1);
          dst[((size_t)(b * NHEADS + h) * SEQ + s) * HDIM + d] = f2bf(acc[m][n][j]);
        }
      }
    }
  }
}

// ---------------------------------------------------------------------------
// Output projection: out = O[4096x1024] * Wo^T. Output dtype per flags[0].
// ---------------------------------------------------------------------------
__global__ __launch_bounds__(256) void out_gemm_kernel(
    const unsigned short* __restrict__ A, const unsigned short* __restrict__ Wo,
    void* __restrict__ outv, const int* __restrict__ flags) {
  __shared__ unsigned short As[128 * 32];
  __shared__ unsigned short Bs[128 * 32];
  const int bm = blockIdx.x * 128, bn = blockIdx.y * 128;
  f32x4 acc[4][4];
#pragma unroll
  for (int m = 0; m < 4; ++m)
#pragma unroll
    for (int n = 0; n < 4; ++n)
#pragma unroll
      for (int j = 0; j < 4; ++j) acc[m][n][j] = 0.f;

  gemm_core(A, Wo, As, Bs, bm, bn, acc);

  const int tid = threadIdx.x, lane = tid & 63, w = tid >> 6;
  const int wm = w >> 1, wn = w & 1, c = lane & 15, g4 = lane >> 4;
  const int f32o = flags[0];
  if (f32o) {
    float* out = (float*)outv;
#pragma unroll
    for (int m = 0; m < 4; ++m)
#pragma unroll
      for (int n = 0; n < 4; ++n) {
        const int col = bn + wn * 64 + n * 16 + c;
#pragma unroll
        for (int j = 0; j < 4; ++j) {
          const int row = bm + wm * 64 + m * 16 + g4 * 4 + j;
          out[(size_t)row * DMODEL + col] = acc[m][n][j];
        }
      }
  } else {
    unsigned short* out = (unsigned short*)outv;
#pragma unroll
    for (int m = 0; m < 4; ++m)
#pragma unroll
      for (int n = 0; n < 4; ++n) {
        const int col = bn + wn * 64 + n * 16 + c;
#pragma unroll
        for (int j = 0; j < 4; ++j) {
          const int row = bm + wm * 64 + m * 16 + g4 * 4 + j;
          out[(size_t)row * DMODEL + col] = f2bf(acc[m][n][j]);
        }
      }
  }
}

// ---------------------------------------------------------------------------
// RoPE in-place on Q and K ([B,H,S,64]). Q additionally pre-scaled by
// 1/sqrt(64) = 0.125 (exact power of 2 in bf16) so flash skips the scale.
// ---------------------------------------------------------------------------
__global__ __launch_bounds__(256) void rope_kernel(unsigned short* __restrict__ q,
                                                   unsigned short* __restrict__ k,
                                                   const int* __restrict__ pos,
                                                   const int* __restrict__ flags) {
  const int idx = blockIdx.x * 256 + threadIdx.x;
  const int tsel = idx >> 21;
  const int p = idx & ((1 << 21) - 1);
  const int j = p & 31;
  const int s = (p >> 5) & (SEQ - 1);
  const int bh = p >> 16;
  const int b = bh >> 4;
  unsigned short* base = tsel ? k : q;
  const int pidx = b * SEQ + s;
  const int pv = flags[1] ? pos[2 * pidx] : pos[pidx];
  const float sc = tsel ? 1.0f : 0.125f;
  const float freq = exp2f((float)j * -0.41524101186092026f);  // log2(10000)/32
  const float ang = (float)pv * freq;
  const float cs = cosf(ang);
  const float sn = sinf(ang);
  unsigned int* wp = (unsigned int*)base + ((p >> 5) * 32 + j);
  const unsigned int u = *wp;
  const float e = bf2f((unsigned short)(u & 0xffffu));
  const float o = bf2f((unsigned short)(u >> 16));
  *wp = (unsigned int)f2bf((e * cs - o * sn) * sc) |
        ((unsigned int)f2bf((e * sn + o * cs) * sc) << 16);
}

// ---------------------------------------------------------------------------
// Flash attention v3 — swapped-operand MFMA. 1024 blocks, 4 waves x 16 q-rows.
// S^T = mfma(K,Q): lane holds one q-row's 16 S values (k over g-groups) ->
// row-reduce = 15 lane-local fmax + 2 shfl. O^T = mfma(V^T, P^T) keeps the
// q-along-lanes layout end to end. K double-buffered, V single-buffered with
// explicit vmcnt(0) before PV. LDS 33.2 KB -> 4 blocks/CU.
// ---------------------------------------------------------------------------
#define MNEG -1e30f
#define QBLK 64
#define LOG2E 1.4426950408889634f
__global__ __launch_bounds__(256, 4) void flash_kernel(
    const unsigned short* __restrict__ q, const unsigned short* __restrict__ k,
    const unsigned short* __restrict__ vt, unsigned short* __restrict__ o) {
  __shared__ unsigned short Ks[2][64 * 64];   // 16 KB double-buffered
  __shared__ unsigned short Vs[64 * 64];      //  8 KB
  __shared__ unsigned short Ps[64 * 72];      //  9 KB (stride 72: b128-aligned rows)

  const int wg = blockIdx.x;                  // 0..1023, sorted big-first
  const int qt = (SEQ / QBLK - 1) - (wg >> 5);
  const int bh = wg & 31;
  const int qbase = qt * QBLK;
  const int tid = threadIdx.x, lane = tid & 63, w = tid >> 6;
  const int c = lane & 15, g = lane >> 4;
  const int wq = w * 16;
  const size_t tb = (size_t)bh * SEQ * HDIM;

  // ---- Q fragments direct to registers (q pre-scaled by 0.125 in rope) ----
  bf16x8 qf[2];
#pragma unroll
  for (int kk = 0; kk < 2; ++kk)
    qf[kk] = *(const bf16x8*)(q + tb + (size_t)(qbase + wq + c) * HDIM + kk * 32 + g * 8);

  // ---- stage K tile 0 ----
#pragma unroll
  for (int i = 0; i < 2; ++i) {
    const int t = tid + i * 256;
    const int r = t >> 3;
    const int sl = (t & 7) ^ (r & 7);
    __builtin_amdgcn_global_load_lds((gas_t)(k + tb + (size_t)r * HDIM + sl * 8),
                                     (las_t)(Ks[0] + t * 8), 16, 0, 0);
  }
  __syncthreads();

  f32x4 acco[4];
#pragma unroll
  for (int n = 0; n < 4; ++n)
#pragma unroll
    for (int j = 0; j < 4; ++j) acco[n][j] = 0.f;
  float m_r = MNEG, l_r = 0.f;

  const int nkv = qt + 1;
  for (int kt = 0; kt < nkv; ++kt) {
    const int p = kt & 1;
    const int kvb = kt * 64;
    // ---- issue V[kt] into Vs (safe: barrier passed => PV[kt-1] done) ----
#pragma unroll
    for (int i = 0; i < 2; ++i) {
      const int t = tid + i * 256;
      const int r = t >> 3;
      const int sl = (t & 7) ^ (r & 7);
      __builtin_amdgcn_global_load_lds((gas_t)(vt + tb + (size_t)r * SEQ + kvb + sl * 8),
                                       (las_t)(Vs + t * 8), 16, 0, 0);
    }
    // ---- prefetch K[kt+1] into other buffer ----
    if (kt + 1 < nkv) {
      const int kvb1 = kvb + 64;
#pragma unroll
      for (int i = 0; i < 2; ++i) {
        const int t = tid + i * 256;
        const int r = t >> 3;
        const int sl = (t & 7) ^ (r & 7);
        __builtin_amdgcn_global_load_lds((gas_t)(k + tb + (size_t)(kvb1 + r) * HDIM + sl * 8),
                                         (las_t)(Ks[p ^ 1] + t * 8), 16, 0, 0);
      }
    }

    // ---- S^T = K Q^T : D col = q (lane c), row = k_local (g*4+jj) ----
    f32x4 accs[4];
#pragma unroll
    for (int n = 0; n < 4; ++n)
#pragma unroll
      for (int j = 0; j < 4; ++j) accs[n][j] = 0.f;
#pragma unroll
    for (int kk = 0; kk < 2; ++kk)
#pragma unroll
      for (int n = 0; n < 4; ++n) {
        const int r = n * 16 + c;
        const int sl = (kk * 4 + g) ^ (r & 7);
        const bf16x8 ak = *(const bf16x8*)&Ks[p][r * 64 + sl * 8];
        accs[n] = __builtin_amdgcn_mfma_f32_16x16x32_bf16(ak, qf[kk], accs[n], 0, 0, 0);
      }

    // ---- causal mask (only on diagonal tile) ----
    const int qg = qbase + wq + c;
    if (kt == qt) {
#pragma unroll
      for (int n = 0; n < 4; ++n)
#pragma unroll
        for (int jj = 0; jj < 4; ++jj)
          if (kvb + n * 16 + g * 4 + jj > qg) accs[n][jj] = MNEG;
    }

    // ---- online softmax: one q-row per lane ----
    float rm = accs[0][0];
#pragma unroll
    for (int n = 0; n < 4; ++n)
#pragma unroll
      for (int jj = 0; jj < 4; ++jj) rm = fmaxf(rm, accs[n][jj]);
    rm = fmaxf(rm, __shfl_xor(rm, 16));
    rm = fmaxf(rm, __shfl_xor(rm, 32));
    const float mn = fmaxf(m_r, rm);
    const float al = exp2f((m_r - mn) * LOG2E);
    float rs = 0.f;
#pragma unroll
    for (int n = 0; n < 4; ++n)
#pragma unroll
      for (int jj = 0; jj < 4; ++jj) {
        const float pv = exp2f((accs[n][jj] - mn) * LOG2E);
        accs[n][jj] = pv;
        rs += pv;
      }
    rs += __shfl_xor(rs, 16);
    rs += __shfl_xor(rs, 32);
    l_r = l_r * al + rs;
    m_r = mn;
#pragma unroll
    for (int n = 0; n < 4; ++n)
#pragma unroll
      for (int jj = 0; jj < 4; ++jj) acco[n][jj] *= al;

    // ---- P^T -> LDS: 4 bf16 (k-consecutive) per n via 8B store ----
#pragma unroll
    for (int n = 0; n < 4; ++n) {
      u16x4 pk4;
#pragma unroll
      for (int jj = 0; jj < 4; ++jj) pk4[jj] = f2bf(accs[n][jj]);
      *(u16x4*)&Ps[(wq + c) * 72 + n * 16 + g * 4] = pk4;
    }

    // ---- wait for V[kt] staging (drains K prefetch too; issued earlier) ----
    asm volatile("s_waitcnt vmcnt(0)" ::: "memory");

    // ---- O^T += V^T P^T ----
#pragma unroll
    for (int kk = 0; kk < 2; ++kk) {
      const bf16x8 pb = *(const bf16x8*)&Ps[(wq + c) * 72 + kk * 32 + g * 8];
#pragma unroll
      for (int n = 0; n < 4; ++n) {
        const int r = n * 16 + c;
        const int sl = (kk * 4 + g) ^ (r & 7);
        const bf16x8 av = *(const bf16x8*)&Vs[r * 64 + sl * 8];
        acco[n] = __builtin_amdgcn_mfma_f32_16x16x32_bf16(av, pb, acco[n], 0, 0, 0);
      }
    }
    __syncthreads();  // publish K[kt+1]; protect Vs/Ks[p] for next tile
  }

  // ---- epilogue: O/l, store [B,S,H*64]; lane c owns row qbase+wq+c ----
  const float rl = 1.f / fmaxf(l_r, 1e-20f);
  const int b = bh >> 4, h = bh & 15;
  const int srow = qbase + wq + c;
#pragma unroll
  for (int n = 0; n < 4; ++n) {
    u16x4 pk;
#pragma unroll
    for (int jj = 0; jj < 4; ++jj) pk[jj] = f2bf(acco[n][jj] * rl);
    *(u16x4*)&o[(size_t)(b * SEQ + srow) * DMODEL + h * 64 + n * 16 + g * 4] = pk;
  }
}

// ---------------------------------------------------------------------------
extern "C" void kernel_launch(void* const* d_in, const int* in_sizes, int n_in,
                              void* d_out, int out_size, void* d_ws, size_t ws_size,
                              hipStream_t stream) {
  (void)in_sizes; (void)n_in; (void)out_size; (void)ws_size;
  const size_t MB = (size_t)1 << 20;
  char* ws = (char*)d_ws;
  unsigned short* xb  = (unsigned short*)(ws);            // 8 MB (reused as ow)
  unsigned short* Wqb = (unsigned short*)(ws + 8 * MB);   // 2 MB each
  unsigned short* Wkb = (unsigned short*)(ws + 10 * MB);
  unsigned short* Wvb = (unsigned short*)(ws + 12 * MB);
  unsigned short* Wob = (unsigned short*)(ws + 14 * MB);
  unsigned short* qw  = (unsigned short*)(ws + 16 * MB);  // 8 MB
  unsigned short* kw  = (unsigned short*)(ws + 24 * MB);  // 8 MB
  unsigned short* vtw = (unsigned short*)(ws + 32 * MB);  // 8 MB
  int* flags          = (int*)(ws + 40 * MB);
  unsigned short* ow  = xb;  // x dead after qkv_gemm

  const dim3 blk(256);
  probe_kernel<<<1, 64, 0, stream>>>((const unsigned int*)d_in[0], (const int*)d_in[5], flags);
  conv_kernel<<<4096, blk, 0, stream>>>(d_in[0], d_in[1], d_in[2], d_in[3], d_in[4], xb, flags);
  qkv_gemm_kernel<<<dim3(32, 8, 3), blk, 0, stream>>>(xb, Wqb, Wkb, Wvb, qw, kw, vtw);
  rope_kernel<<<16384, blk, 0, stream>>>(qw, kw, (const int*)d_in[5], flags);
  flash_kernel<<<dim3(1024), blk, 0, stream>>>(qw, kw, vtw, ow);
  out_gemm_kernel<<<dim3(32, 8), blk, 0, stream>>>(ow, Wob, d_out, flags);
}